// Round 18
// baseline (856.287 us; speedup 1.0000x reference)
//
#include <hip/hip_runtime.h>
#include <hip/hip_bf16.h>

#define Hh   64      // LSTM hidden
#define G4   256     // 4*H gate width
#define Dd   128     // input feature dim
#define Bsz  256     // batch
#define Tt   1024    // time steps
#define NOUT 10      // dense classes

typedef __bf16  bf16x8 __attribute__((ext_vector_type(8)));
typedef __bf16  bf16x4 __attribute__((ext_vector_type(4)));
typedef float   f32x4v __attribute__((ext_vector_type(4)));

// rho = 64g + 16w + 4kq + r  <->  original gate column = 64g + hidx with
// hidx = 32(w>>1) + 8kq + 4(w&1) + r.
__device__ __forceinline__ int rho_origcol(int rho) {
    const int g  = rho >> 6;
    const int s  = (rho >> 5) & 1;
    const int d2 = (rho >> 4) & 1;
    const int kq = (rho >> 2) & 3;
    const int dl = rho & 3;
    return g * 64 + (32 * s + 8 * kq + 4 * d2 + dl);
}

// xw layout: NATURAL [b][t][rho] bf16. k2 gathers via per-lane-addressed
// global_load_lds with the R16-verified swizzle: DMA instr i=2w+j, lane l ->
// batch m' = 2i+(l>>5), chunk sch = ((l&31)-m')&31; dest i*1024 + l*16.
// C-init reads at rd_off (R16-verified). TWO groups per block (dual-scan).

__device__ __forceinline__ void gld_lds16(const void* g, void* l) {
    __builtin_amdgcn_global_load_lds(
        (const __attribute__((address_space(1))) unsigned int*)g,
        (__attribute__((address_space(3))) unsigned int*)l, 16, 0, 0);
}

// ---------------------------------------------------------------------------
// K0: Wt[rho][k] = bf16(scale * W[k][origcol]), bias2[rho] = scale*b + offs.
// ---------------------------------------------------------------------------
__global__ __launch_bounds__(128)
void k0_prep(const float* __restrict__ W, const float* __restrict__ b,
             __bf16* __restrict__ Wt, float* __restrict__ bias2) {
    const int rho = blockIdx.x;
    const int k   = threadIdx.x;
    const int col = rho_origcol(rho);
    const bool isg = ((rho >> 6) == 2);
    const float sc = isg ? 1.f : 0.2f;
    Wt[(size_t)rho * Dd + k] = (__bf16)(sc * W[(size_t)k * G4 + col]);
    if (k == 0) bias2[rho] = sc * b[col] + (isg ? 0.f : 0.5f);
}

// ---------------------------------------------------------------------------
// K1: xw = x @ Wt + bias2 via MFMA, NATURAL [row][rho] store (proven R16).
// ---------------------------------------------------------------------------
#define K1_RT 8   // 128 rows/block

__global__ __launch_bounds__(256)
void k1_mfma(const float* __restrict__ x, const __bf16* __restrict__ Wt,
             const float* __restrict__ bias, __bf16* __restrict__ xw) {
    const int tid = threadIdx.x;
    const int w   = tid >> 6;
    const int l   = tid & 63;
    const int r16 = l & 15;
    const int kq  = l >> 4;
    const size_t rowbase = (size_t)blockIdx.x * (16 * K1_RT);

    bf16x8 bfr[4][4];
    float  bval[4];
#pragma unroll
    for (int ct = 0; ct < 4; ++ct) {
        const int col = w * 64 + ct * 16 + r16;
        const __bf16* wp = Wt + (size_t)col * Dd + kq * 8;
#pragma unroll
        for (int kk = 0; kk < 4; ++kk)
            bfr[ct][kk] = *(const bf16x8*)(wp + kk * 32);
        bval[ct] = bias[col];
    }

    for (int rt = 0; rt < K1_RT; ++rt) {
        const size_t arow = rowbase + rt * 16 + r16;
        const float* xr = x + arow * Dd + kq * 8;
        bf16x8 afr[4];
#pragma unroll
        for (int kk = 0; kk < 4; ++kk) {
            const float4 lo = *(const float4*)(xr + kk * 32);
            const float4 hi = *(const float4*)(xr + kk * 32 + 4);
            afr[kk][0] = (__bf16)lo.x; afr[kk][1] = (__bf16)lo.y;
            afr[kk][2] = (__bf16)lo.z; afr[kk][3] = (__bf16)lo.w;
            afr[kk][4] = (__bf16)hi.x; afr[kk][5] = (__bf16)hi.y;
            afr[kk][6] = (__bf16)hi.z; afr[kk][7] = (__bf16)hi.w;
        }
        f32x4v acc[4];
#pragma unroll
        for (int ct = 0; ct < 4; ++ct)
            acc[ct] = (f32x4v){bval[ct], bval[ct], bval[ct], bval[ct]};
#pragma unroll
        for (int ct = 0; ct < 4; ++ct)
#pragma unroll
            for (int kk = 0; kk < 4; ++kk)
                acc[ct] = __builtin_amdgcn_mfma_f32_16x16x32_bf16(
                              afr[kk], bfr[ct][kk], acc[ct], 0, 0, 0);

        const size_t orow0 = rowbase + rt * 16 + kq * 4;
#pragma unroll
        for (int ct = 0; ct < 4; ++ct) {
            const int col = w * 64 + ct * 16 + r16;
#pragma unroll
            for (int rr = 0; rr < 4; ++rr)
                xw[(orow0 + rr) * G4 + col] = (__bf16)acc[ct][rr];
        }
    }
}

// ---------------------------------------------------------------------------
// K2: DUAL-SCAN LSTM. Block = 4 waves, TWO independent 16-batch groups; the
// two chains interleave within each wave so group B's issue fills group A's
// latency (barrier/waits paid once for both). R16's verified DMA swizzle,
// rd_off, hx exchange, per-step raw barrier; SST=4 (LDS 137KB).
// ---------------------------------------------------------------------------
#define SST 4   // steps per superstep

__global__ __launch_bounds__(256, 1)
void k2_scan(const __bf16* __restrict__ xw, const float* __restrict__ U,
             float* __restrict__ hout) {
    const int tid = threadIdx.x;
    const int w   = tid >> 6;       // wave 0..3
    const int l   = tid & 63;
    const int kq  = l >> 4;
    const int m   = l & 15;
    const int s_  = w >> 1, d2 = w & 1;
    const int G0  = blockIdx.x * 2; // groups G0, G0+1

    __shared__ __align__(16) unsigned char ring[2][2][SST][8192];  // 128KB
    __shared__ __align__(16) __bf16 hx[2][2][16][72];              // 9KB

    // A-frags (shared by both groups): au[g][ks]
    bf16x8 au[4][2];
#pragma unroll
    for (int g = 0; g < 4; ++g) {
        const float sc = (g == 2) ? 1.f : 0.2f;
        const int col = rho_origcol(64 * g + 16 * w + m);
#pragma unroll
        for (int ks = 0; ks < 2; ++ks)
#pragma unroll
            for (int j = 0; j < 8; ++j)
                au[g][ks][j] = (__bf16)(sc * U[(size_t)(ks * 32 + kq * 8 + j) * G4 + col]);
    }

    float c4[2][4], hv4[2][4];
#pragma unroll
    for (int g2 = 0; g2 < 2; ++g2)
#pragma unroll
        for (int r = 0; r < 4; ++r) { c4[g2][r] = 0.f; hv4[g2][r] = 0.f; }

    // zero hx[*][1] (read by the very first step, rp = 1)
    {
        const bf16x4 z4 = {(__bf16)0.f, (__bf16)0.f, (__bf16)0.f, (__bf16)0.f};
#pragma unroll
        for (int g2 = 0; g2 < 2; ++g2)
            *(bf16x4*)&hx[g2][1][m][32 * s_ + 8 * kq + 4 * d2] = z4;
    }

    // per-lane DMA sources (R16-verified swizzle), per group
    const char* xwc = (const char*)xw;
    const char* srcp[2][2];
#pragma unroll
    for (int g2 = 0; g2 < 2; ++g2)
#pragma unroll
        for (int j = 0; j < 2; ++j) {
            const int i  = 2 * w + j;
            const int mp = 2 * i + (l >> 5);
            const int sch = ((l & 31) - mp) & 31;
            srcp[g2][j] = xwc + (size_t)(16 * (G0 + g2) + mp) * 524288
                          + (size_t)sch * 16;
        }
    int rd_off[4];
#pragma unroll
    for (int g = 0; g < 4; ++g)
        rd_off[g] = m * 512 + (((8 * g + 2 * w + (kq >> 1) + m) & 31) << 4)
                    + ((kq & 1) << 3);

    // prologue: buf-major issue order so vmcnt(16) waits one superstep batch
#pragma unroll
    for (int buf = 0; buf < 2; ++buf)
#pragma unroll
        for (int g2 = 0; g2 < 2; ++g2)
#pragma unroll
            for (int stp = 0; stp < SST; ++stp)
#pragma unroll
                for (int j = 0; j < 2; ++j)
                    gld_lds16(srcp[g2][j] + (size_t)(buf * SST + stp) * 512,
                              &ring[g2][buf][stp][(2 * w + j) * 1024]);
    __syncthreads();   // full drain + publishes hx zeros

    uint2  dz[2][4];
    f32x4v accN[2][4];
    bf16x8 bh0[2], bh1[2];

    for (int S = 0; S < Tt / SST; ++S) {
        const int cur = S & 1;

        // superstep batch (16/wave) done; barrier -> all waves' loads visible
        asm volatile("s_waitcnt vmcnt(16)" ::: "memory");
        __builtin_amdgcn_sched_barrier(0);
        __builtin_amdgcn_s_barrier();
        __builtin_amdgcn_sched_barrier(0);

        // superstep-top C-init for stp 0, both groups
#pragma unroll
        for (int g2 = 0; g2 < 2; ++g2)
#pragma unroll
            for (int g = 0; g < 4; ++g)
                dz[g2][g] = *(const uint2*)&ring[g2][cur][0][rd_off[g]];
#pragma unroll
        for (int g2 = 0; g2 < 2; ++g2)
#pragma unroll
            for (int g = 0; g < 4; ++g) {
                accN[g2][g][0] = __builtin_bit_cast(float, dz[g2][g].x << 16);
                accN[g2][g][1] = __builtin_bit_cast(float, dz[g2][g].x & 0xFFFF0000u);
                accN[g2][g][2] = __builtin_bit_cast(float, dz[g2][g].y << 16);
                accN[g2][g][3] = __builtin_bit_cast(float, dz[g2][g].y & 0xFFFF0000u);
            }

#pragma unroll
        for (int stp = 0; stp < SST; ++stp) {
            const int rp = (stp + 1) & 1;

            // ---- post-barrier critical path (both groups interleaved)
#pragma unroll
            for (int g2 = 0; g2 < 2; ++g2) {
                bh0[g2] = *(const bf16x8*)&hx[g2][rp][m][8 * kq];
                bh1[g2] = *(const bf16x8*)&hx[g2][rp][m][32 + 8 * kq];
            }

            f32x4v acc[2][4];
#pragma unroll
            for (int g2 = 0; g2 < 2; ++g2)
#pragma unroll
                for (int g = 0; g < 4; ++g) {
                    acc[g2][g] = __builtin_amdgcn_mfma_f32_16x16x32_bf16(
                                     au[g][0], bh0[g2], accN[g2][g], 0, 0, 0);
                    acc[g2][g] = __builtin_amdgcn_mfma_f32_16x16x32_bf16(
                                     au[g][1], bh1[g2], acc[g2][g], 0, 0, 0);
                }

#pragma unroll
            for (int g2 = 0; g2 < 2; ++g2) {
                bf16x4 hb;
#pragma unroll
                for (int r = 0; r < 4; ++r) {
                    const float gi = __builtin_amdgcn_fmed3f(acc[g2][0][r], 0.f, 1.f);
                    const float gf = __builtin_amdgcn_fmed3f(acc[g2][1][r], 0.f, 1.f);
                    const float gg = fmaxf(acc[g2][2][r], 0.f);
                    const float go = __builtin_amdgcn_fmed3f(acc[g2][3][r], 0.f, 1.f);
                    c4[g2][r] = fmaf(gf, c4[g2][r], gi * gg);
                    hv4[g2][r] = go * fmaxf(c4[g2][r], 0.f);
                    hb[r] = (__bf16)hv4[g2][r];
                }
                *(bf16x4*)&hx[g2][stp & 1][m][32 * s_ + 8 * kq + 4 * d2] = hb;
            }

            // pin writes before prestage reads (so lgkmcnt(8) covers writes)
            __builtin_amdgcn_sched_barrier(0);

            if (stp < SST - 1) {
#pragma unroll
                for (int g2 = 0; g2 < 2; ++g2)
#pragma unroll
                    for (int g = 0; g < 4; ++g)
                        dz[g2][g] = *(const uint2*)&ring[g2][cur][stp + 1][rd_off[g]];
                asm volatile("s_waitcnt lgkmcnt(8)" ::: "memory");
            } else {
                asm volatile("s_waitcnt lgkmcnt(0)" ::: "memory");
            }
            __builtin_amdgcn_sched_barrier(0);
            __builtin_amdgcn_s_barrier();
            __builtin_amdgcn_sched_barrier(0);

            if (stp < SST - 1) {
#pragma unroll
                for (int g2 = 0; g2 < 2; ++g2)
#pragma unroll
                    for (int g = 0; g < 4; ++g) {
                        accN[g2][g][0] = __builtin_bit_cast(float, dz[g2][g].x << 16);
                        accN[g2][g][1] = __builtin_bit_cast(float, dz[g2][g].x & 0xFFFF0000u);
                        accN[g2][g][2] = __builtin_bit_cast(float, dz[g2][g].y << 16);
                        accN[g2][g][3] = __builtin_bit_cast(float, dz[g2][g].y & 0xFFFF0000u);
                    }
            }
        }

        // issue superstep S+2 into buf[cur] (all reads retired at stp3 barrier)
        {
            int tn0 = (S + 2) * SST;
            if (tn0 > Tt - SST) tn0 = Tt - SST;
#pragma unroll
            for (int g2 = 0; g2 < 2; ++g2)
#pragma unroll
                for (int stp = 0; stp < SST; ++stp)
#pragma unroll
                    for (int j = 0; j < 2; ++j)
                        gld_lds16(srcp[g2][j] + (size_t)(tn0 + stp) * 512,
                                  &ring[g2][cur][stp][(2 * w + j) * 1024]);
        }
    }

    // final h: hidx = 32s_ + 8kq + 4d2 + r, batch = 16(G0+g2)+m
#pragma unroll
    for (int g2 = 0; g2 < 2; ++g2)
#pragma unroll
        for (int r = 0; r < 4; ++r)
            hout[(size_t)((G0 + g2) * 16 + m) * Hh + 32 * s_ + 8 * kq + 4 * d2 + r]
                = hv4[g2][r];
}

// ---------------------------------------------------------------------------
// K3: out[r,:] = softmax(h[r,:] @ Wd + bd). One block, thread = batch row.
// ---------------------------------------------------------------------------
__global__ __launch_bounds__(256)
void k3_dense(const float* __restrict__ hin, const float* __restrict__ Wd,
              const float* __restrict__ bd, float* __restrict__ out) {
    __shared__ float wd[Hh * NOUT];
    __shared__ float bds[NOUT];
    for (int i = threadIdx.x; i < Hh * NOUT; i += blockDim.x) wd[i] = Wd[i];
    if (threadIdx.x < NOUT) bds[threadIdx.x] = bd[threadIdx.x];
    __syncthreads();

    const int r = threadIdx.x;
    if (r < Bsz) {
        float hrow[Hh];
#pragma unroll
        for (int j = 0; j < Hh; ++j) hrow[j] = hin[(size_t)r * Hh + j];
        float logits[NOUT];
#pragma unroll
        for (int o = 0; o < NOUT; ++o) {
            float acc = bds[o];
#pragma unroll
            for (int j = 0; j < Hh; ++j) acc = fmaf(hrow[j], wd[j * NOUT + o], acc);
            logits[o] = acc;
        }
        float mx = logits[0];
#pragma unroll
        for (int o = 1; o < NOUT; ++o) mx = fmaxf(mx, logits[o]);
        float s = 0.f;
#pragma unroll
        for (int o = 0; o < NOUT; ++o) { logits[o] = expf(logits[o] - mx); s += logits[o]; }
        const float inv = 1.f / s;
#pragma unroll
        for (int o = 0; o < NOUT; ++o) out[(size_t)r * NOUT + o] = logits[o] * inv;
    }
}

// ---------------------------------------------------------------------------
extern "C" void kernel_launch(void* const* d_in, const int* in_sizes, int n_in,
                              void* d_out, int out_size, void* d_ws, size_t ws_size,
                              hipStream_t stream) {
    const float* x  = (const float*)d_in[0];
    const float* W  = (const float*)d_in[1];
    const float* U  = (const float*)d_in[2];
    const float* b  = (const float*)d_in[3];
    const float* Wd = (const float*)d_in[4];
    const float* bd = (const float*)d_in[5];
    float* out = (float*)d_out;

    const size_t xw_bytes = (size_t)Bsz * Tt * G4 * sizeof(__bf16);   // 128 MiB
    __bf16* xw    = (__bf16*)d_ws;
    float*  hbuf  = (float*)((char*)d_ws + xw_bytes);                 // 64 KB
    __bf16* Wt    = (__bf16*)((char*)hbuf + (size_t)Bsz * Hh * sizeof(float));
    float*  bias2 = (float*)((char*)Wt + (size_t)G4 * Dd * sizeof(__bf16));

    k0_prep<<<G4, Dd, 0, stream>>>(W, b, Wt, bias2);
    k1_mfma<<<(Bsz * Tt) / (16 * K1_RT), 256, 0, stream>>>(x, Wt, bias2, xw);
    k2_scan<<<Bsz / 32, 256, 0, stream>>>(xw, U, hbuf);
    k3_dense<<<1, 256, 0, stream>>>(hbuf, Wd, bd, out);
}

// Round 19
// 548.002 us; speedup vs baseline: 1.5626x; 1.5626x over previous
//
#include <hip/hip_runtime.h>
#include <hip/hip_bf16.h>

#define Hh   64      // LSTM hidden
#define G4   256     // 4*H gate width
#define Dd   128     // input feature dim
#define Bsz  256     // batch
#define Tt   1024    // time steps
#define NOUT 10      // dense classes

typedef __bf16  bf16x8 __attribute__((ext_vector_type(8)));
typedef __bf16  bf16x4 __attribute__((ext_vector_type(4)));
typedef float   f32x4v __attribute__((ext_vector_type(4)));

// rho = 64g + 16w + 4kq + r  <->  original gate column = 64g + hidx with
// hidx = 32(w>>1) + 8kq + 4(w&1) + r.
__device__ __forceinline__ int rho_origcol(int rho) {
    const int g  = rho >> 6;
    const int s  = (rho >> 5) & 1;
    const int d2 = (rho >> 4) & 1;
    const int kq = (rho >> 2) & 3;
    const int dl = rho & 3;
    return g * 64 + (32 * s + 8 * kq + 4 * d2 + dl);
}

// xw layout: NATURAL [b][t][rho] bf16 -> byte = b*524288 + t*512 + rho*2.
// k2 gathers per step via global_load_lds with PER-LANE global source
// addresses: DMA instr i=2w+j, lane l -> batch m' = 2i+(l>>5),
// chunk sch = ((l&31)-m')&31; dest i*1024 + l*16 (swizzled LDS layout).

__device__ __forceinline__ void gld_lds16(const void* g, void* l) {
    __builtin_amdgcn_global_load_lds(
        (const __attribute__((address_space(1))) unsigned int*)g,
        (__attribute__((address_space(3))) unsigned int*)l, 16, 0, 0);
}

// ---------------------------------------------------------------------------
// K0: Wt[rho][k] = bf16(scale * W[k][origcol]), bias2[rho] = scale*b + offs.
// ---------------------------------------------------------------------------
__global__ __launch_bounds__(128)
void k0_prep(const float* __restrict__ W, const float* __restrict__ b,
             __bf16* __restrict__ Wt, float* __restrict__ bias2) {
    const int rho = blockIdx.x;
    const int k   = threadIdx.x;
    const int col = rho_origcol(rho);
    const bool isg = ((rho >> 6) == 2);
    const float sc = isg ? 1.f : 0.2f;
    Wt[(size_t)rho * Dd + k] = (__bf16)(sc * W[(size_t)k * G4 + col]);
    if (k == 0) bias2[rho] = sc * b[col] + (isg ? 0.f : 0.5f);
}

// ---------------------------------------------------------------------------
// K1: xw = x @ Wt + bias2 via MFMA, NATURAL [row][rho] store.
// ---------------------------------------------------------------------------
#define K1_RT 8   // 128 rows/block

__global__ __launch_bounds__(256)
void k1_mfma(const float* __restrict__ x, const __bf16* __restrict__ Wt,
             const float* __restrict__ bias, __bf16* __restrict__ xw) {
    const int tid = threadIdx.x;
    const int w   = tid >> 6;
    const int l   = tid & 63;
    const int r16 = l & 15;
    const int kq  = l >> 4;
    const size_t rowbase = (size_t)blockIdx.x * (16 * K1_RT);

    bf16x8 bfr[4][4];
    float  bval[4];
#pragma unroll
    for (int ct = 0; ct < 4; ++ct) {
        const int col = w * 64 + ct * 16 + r16;
        const __bf16* wp = Wt + (size_t)col * Dd + kq * 8;
#pragma unroll
        for (int kk = 0; kk < 4; ++kk)
            bfr[ct][kk] = *(const bf16x8*)(wp + kk * 32);
        bval[ct] = bias[col];
    }

    for (int rt = 0; rt < K1_RT; ++rt) {
        const size_t arow = rowbase + rt * 16 + r16;
        const float* xr = x + arow * Dd + kq * 8;
        bf16x8 afr[4];
#pragma unroll
        for (int kk = 0; kk < 4; ++kk) {
            const float4 lo = *(const float4*)(xr + kk * 32);
            const float4 hi = *(const float4*)(xr + kk * 32 + 4);
            afr[kk][0] = (__bf16)lo.x; afr[kk][1] = (__bf16)lo.y;
            afr[kk][2] = (__bf16)lo.z; afr[kk][3] = (__bf16)lo.w;
            afr[kk][4] = (__bf16)hi.x; afr[kk][5] = (__bf16)hi.y;
            afr[kk][6] = (__bf16)hi.z; afr[kk][7] = (__bf16)hi.w;
        }
        f32x4v acc[4];
#pragma unroll
        for (int ct = 0; ct < 4; ++ct)
            acc[ct] = (f32x4v){bval[ct], bval[ct], bval[ct], bval[ct]};
#pragma unroll
        for (int ct = 0; ct < 4; ++ct)
#pragma unroll
            for (int kk = 0; kk < 4; ++kk)
                acc[ct] = __builtin_amdgcn_mfma_f32_16x16x32_bf16(
                              afr[kk], bfr[ct][kk], acc[ct], 0, 0, 0);

        const size_t orow0 = rowbase + rt * 16 + kq * 4;
#pragma unroll
        for (int ct = 0; ct < 4; ++ct) {
            const int col = w * 64 + ct * 16 + r16;
#pragma unroll
            for (int rr = 0; rr < 4; ++rr)
                xw[(orow0 + rr) * G4 + col] = (__bf16)acc[ct][rr];
        }
    }
}

// ---------------------------------------------------------------------------
// K2: LSTM scan, 4 cooperating waves per 16-batch group, 1 group/block,
// 16 blocks. Superstep DMA ring (depth-2 supersteps, counted vmcnt(16)),
// prestage + counted lgkmcnt(4), fmed3 gates, one raw barrier per step.
// ---------------------------------------------------------------------------
#define SST 8   // steps per superstep

__global__ __launch_bounds__(256, 1)
void k2_scan(const __bf16* __restrict__ xw, const float* __restrict__ U,
             float* __restrict__ hout) {
    const int tid = threadIdx.x;
    const int w   = tid >> 6;       // wave 0..3
    const int l   = tid & 63;
    const int kq  = l >> 4;
    const int m   = l & 15;
    const int s_  = w >> 1, d2 = w & 1;
    const int G   = blockIdx.x;     // group 0..15

    __shared__ __align__(16) unsigned char ring[2][SST][8192];     // 128KB
    __shared__ __align__(16) __bf16 hx[2][16][72];                 // 4.5KB

    // A-frags: au[g][ks][j] = sc_g * U[32ks + 8kq + j][origcol(64g+16w+m)]
    bf16x8 au[4][2];
#pragma unroll
    for (int g = 0; g < 4; ++g) {
        const float sc = (g == 2) ? 1.f : 0.2f;
        const int col = rho_origcol(64 * g + 16 * w + m);
#pragma unroll
        for (int ks = 0; ks < 2; ++ks)
#pragma unroll
            for (int j = 0; j < 8; ++j)
                au[g][ks][j] = (__bf16)(sc * U[(size_t)(ks * 32 + kq * 8 + j) * G4 + col]);
    }

    float c4[4]  = {0.f, 0.f, 0.f, 0.f};
    float hv4[4] = {0.f, 0.f, 0.f, 0.f};

    // zero hx[1] (read by the very first step, rp = 1)
    {
        const bf16x4 z4 = {(__bf16)0.f, (__bf16)0.f, (__bf16)0.f, (__bf16)0.f};
        *(bf16x4*)&hx[1][m][32 * s_ + 8 * kq + 4 * d2] = z4;
    }

    // per-lane DMA source offsets for this wave's instrs i = 2w + j, j=0,1:
    const char* xwc = (const char*)xw;
    const char* src_j[2];
#pragma unroll
    for (int j = 0; j < 2; ++j) {
        const int i  = 2 * w + j;
        const int mp = 2 * i + (l >> 5);
        const int sch = ((l & 31) - mp) & 31;
        src_j[j] = xwc + (size_t)(16 * G + mp) * 524288 + (size_t)sch * 16;
    }
    // C-init read offsets (loop-invariant per lane):
    int rd_off[4];
#pragma unroll
    for (int g = 0; g < 4; ++g)
        rd_off[g] = m * 512 + (((8 * g + 2 * w + (kq >> 1) + m) & 31) << 4)
                    + ((kq & 1) << 3);

    // prologue: issue buf0 (steps 0..7) and buf1 (steps 8..15): 16/wave
#pragma unroll
    for (int buf = 0; buf < 2; ++buf)
#pragma unroll
        for (int stp = 0; stp < SST; ++stp)
#pragma unroll
            for (int j = 0; j < 2; ++j)
                gld_lds16(src_j[j] + (size_t)(buf * SST + stp) * 512,
                          &ring[buf][stp][(2 * w + j) * 1024]);
    __syncthreads();   // once: drains prologue DMAs + publishes hx[1] zeros

    uint2  dz[4];
    f32x4v accN[4];
    bf16x8 bh0, bh1;

    for (int S = 0; S < Tt / SST; ++S) {
        const int cur = S & 1;

        // own 16 superstep-S loads done; barrier -> ALL waves' loads visible
        asm volatile("s_waitcnt vmcnt(16)" ::: "memory");
        __builtin_amdgcn_sched_barrier(0);
        __builtin_amdgcn_s_barrier();
        __builtin_amdgcn_sched_barrier(0);

        // superstep-top C-init for stp 0
#pragma unroll
        for (int g = 0; g < 4; ++g)
            dz[g] = *(const uint2*)&ring[cur][0][rd_off[g]];
#pragma unroll
        for (int g = 0; g < 4; ++g) {
            accN[g][0] = __builtin_bit_cast(float, dz[g].x << 16);
            accN[g][1] = __builtin_bit_cast(float, dz[g].x & 0xFFFF0000u);
            accN[g][2] = __builtin_bit_cast(float, dz[g].y << 16);
            accN[g][3] = __builtin_bit_cast(float, dz[g].y & 0xFFFF0000u);
        }

#pragma unroll
        for (int stp = 0; stp < SST; ++stp) {
            const int rp = (stp + 1) & 1;

            bh0 = *(const bf16x8*)&hx[rp][m][8 * kq];
            bh1 = *(const bf16x8*)&hx[rp][m][32 + 8 * kq];

            f32x4v acc[4];
#pragma unroll
            for (int g = 0; g < 4; ++g) {
                acc[g] = __builtin_amdgcn_mfma_f32_16x16x32_bf16(au[g][0], bh0, accN[g], 0, 0, 0);
                acc[g] = __builtin_amdgcn_mfma_f32_16x16x32_bf16(au[g][1], bh1, acc[g], 0, 0, 0);
            }

            bf16x4 hb;
#pragma unroll
            for (int r = 0; r < 4; ++r) {
                const float gi = __builtin_amdgcn_fmed3f(acc[0][r], 0.f, 1.f);
                const float gf = __builtin_amdgcn_fmed3f(acc[1][r], 0.f, 1.f);
                const float gg = fmaxf(acc[2][r], 0.f);
                const float go = __builtin_amdgcn_fmed3f(acc[3][r], 0.f, 1.f);
                c4[r] = fmaf(gf, c4[r], gi * gg);
                hv4[r] = go * fmaxf(c4[r], 0.f);
                hb[r] = (__bf16)hv4[r];
            }

            *(bf16x4*)&hx[stp & 1][m][32 * s_ + 8 * kq + 4 * d2] = hb;

            if (stp < SST - 1) {
#pragma unroll
                for (int g = 0; g < 4; ++g)
                    dz[g] = *(const uint2*)&ring[cur][stp + 1][rd_off[g]];
                asm volatile("s_waitcnt lgkmcnt(4)" ::: "memory");  // write drained
            } else {
                asm volatile("s_waitcnt lgkmcnt(0)" ::: "memory");
            }
            __builtin_amdgcn_sched_barrier(0);
            __builtin_amdgcn_s_barrier();
            __builtin_amdgcn_sched_barrier(0);

            if (stp < SST - 1) {
#pragma unroll
                for (int g = 0; g < 4; ++g) {
                    accN[g][0] = __builtin_bit_cast(float, dz[g].x << 16);
                    accN[g][1] = __builtin_bit_cast(float, dz[g].x & 0xFFFF0000u);
                    accN[g][2] = __builtin_bit_cast(float, dz[g].y << 16);
                    accN[g][3] = __builtin_bit_cast(float, dz[g].y & 0xFFFF0000u);
                }
            }
        }

        // issue superstep S+2 into buf[cur] (all reads retired: stp7 barrier)
        {
            int tn0 = (S + 2) * SST;
            if (tn0 > Tt - SST) tn0 = Tt - SST;
#pragma unroll
            for (int stp = 0; stp < SST; ++stp)
#pragma unroll
                for (int j = 0; j < 2; ++j)
                    gld_lds16(src_j[j] + (size_t)(tn0 + stp) * 512,
                              &ring[cur][stp][(2 * w + j) * 1024]);
        }
    }

#pragma unroll
    for (int r = 0; r < 4; ++r)
        hout[(size_t)(G * 16 + m) * Hh + 32 * s_ + 8 * kq + 4 * d2 + r] = hv4[r];
}

// ---------------------------------------------------------------------------
// K3: out[r,:] = softmax(h[r,:] @ Wd + bd). One block, thread = batch row.
// ---------------------------------------------------------------------------
__global__ __launch_bounds__(256)
void k3_dense(const float* __restrict__ hin, const float* __restrict__ Wd,
              const float* __restrict__ bd, float* __restrict__ out) {
    __shared__ float wd[Hh * NOUT];
    __shared__ float bds[NOUT];
    for (int i = threadIdx.x; i < Hh * NOUT; i += blockDim.x) wd[i] = Wd[i];
    if (threadIdx.x < NOUT) bds[threadIdx.x] = bd[threadIdx.x];
    __syncthreads();

    const int r = threadIdx.x;
    if (r < Bsz) {
        float hrow[Hh];
#pragma unroll
        for (int j = 0; j < Hh; ++j) hrow[j] = hin[(size_t)r * Hh + j];
        float logits[NOUT];
#pragma unroll
        for (int o = 0; o < NOUT; ++o) {
            float acc = bds[o];
#pragma unroll
            for (int j = 0; j < Hh; ++j) acc = fmaf(hrow[j], wd[j * NOUT + o], acc);
            logits[o] = acc;
        }
        float mx = logits[0];
#pragma unroll
        for (int o = 1; o < NOUT; ++o) mx = fmaxf(mx, logits[o]);
        float s = 0.f;
#pragma unroll
        for (int o = 0; o < NOUT; ++o) { logits[o] = expf(logits[o] - mx); s += logits[o]; }
        const float inv = 1.f / s;
#pragma unroll
        for (int o = 0; o < NOUT; ++o) out[(size_t)r * NOUT + o] = logits[o] * inv;
    }
}

// ---------------------------------------------------------------------------
extern "C" void kernel_launch(void* const* d_in, const int* in_sizes, int n_in,
                              void* d_out, int out_size, void* d_ws, size_t ws_size,
                              hipStream_t stream) {
    const float* x  = (const float*)d_in[0];
    const float* W  = (const float*)d_in[1];
    const float* U  = (const float*)d_in[2];
    const float* b  = (const float*)d_in[3];
    const float* Wd = (const float*)d_in[4];
    const float* bd = (const float*)d_in[5];
    float* out = (float*)d_out;

    const size_t xw_bytes = (size_t)Bsz * Tt * G4 * sizeof(__bf16);   // 128 MiB
    __bf16* xw    = (__bf16*)d_ws;
    float*  hbuf  = (float*)((char*)d_ws + xw_bytes);                 // 64 KB
    __bf16* Wt    = (__bf16*)((char*)hbuf + (size_t)Bsz * Hh * sizeof(float));
    float*  bias2 = (float*)((char*)Wt + (size_t)G4 * Dd * sizeof(__bf16));

    k0_prep<<<G4, Dd, 0, stream>>>(W, b, Wt, bias2);
    k1_mfma<<<(Bsz * Tt) / (16 * K1_RT), 256, 0, stream>>>(x, Wt, bias2, xw);
    k2_scan<<<Bsz / 16, 256, 0, stream>>>(xw, U, hbuf);
    k3_dense<<<1, 256, 0, stream>>>(hbuf, Wd, bd, out);
}